// Round 6
// baseline (121.939 us; speedup 1.0000x reference)
//
#include <hip/hip_runtime.h>
#include <math.h>

#define T_LEN   4000
#define CHUNK   256            // 64 lanes * 4 elements
#define NCHUNK  16             // chunks per row; chunk 15: lanes 0..39 valid

__device__ __forceinline__ float pcen_elem(float xv, float s) {
    const float ALPHA = 0.98f;
    const float DELTA = 2.0f;
    const float SQRT_DELTA = 1.4142135623730951f;
    const float EPS = 1e-6f;
    float p = exp2f(-ALPHA * log2f(s + EPS));
    return sqrtf(fmaf(xv, p, DELTA)) - SQRT_DELTA;
}

// local affine compose over a lane's 4 consecutive elems (b component only)
__device__ __forceinline__ float compose4(float4 v, bool is_t0) {
    const float ALPHA = 0.98f;
    const float OMA   = 0.02f;
    float b = is_t0 ? v.x : OMA * v.x;     // t=0: A=0, B=x0
    b = fmaf(ALPHA, b, OMA * v.y);
    b = fmaf(ALPHA, b, OMA * v.z);
    b = fmaf(ALPHA, b, OMA * v.w);
    return b;
}

// constant-coefficient Kogge-Stone inclusive scan across 64 lanes
__device__ __forceinline__ float ks_scan(float b, int lane) {
    const float R1  = 0.92236816f;   // alpha^4
    const float R2  = 0.85076302f;   // alpha^8
    const float R4  = 0.72379773f;   // alpha^16
    const float R8  = 0.52388316f;   // alpha^32
    const float R16 = 0.27445340f;   // alpha^64
    const float R32 = 0.07532467f;   // alpha^128
    float bi = b;
    { float bu = __shfl_up(bi, 1);  bi = fmaf(lane >= 1  ? R1  : 0.f, bu, bi); }
    { float bu = __shfl_up(bi, 2);  bi = fmaf(lane >= 2  ? R2  : 0.f, bu, bi); }
    { float bu = __shfl_up(bi, 4);  bi = fmaf(lane >= 4  ? R4  : 0.f, bu, bi); }
    { float bu = __shfl_up(bi, 8);  bi = fmaf(lane >= 8  ? R8  : 0.f, bu, bi); }
    { float bu = __shfl_up(bi, 16); bi = fmaf(lane >= 16 ? R16 : 0.f, bu, bi); }
    { float bu = __shfl_up(bi, 32); bi = fmaf(lane >= 32 ? R32 : 0.f, bu, bi); }
    return bi;
}

__global__ __launch_bounds__(256, 6) void pcen_kernel(const float* __restrict__ x,
                                                      float* __restrict__ out,
                                                      int nrows) {
    const float ALPHA = 0.98f;
    const float OMA   = 0.02f;
    const float R1   = 0.92236816f;
    const float R2   = 0.85076302f;
    const float R4   = 0.72379773f;
    const float R8   = 0.52388316f;
    const float R16  = 0.27445340f;
    const float R32  = 0.07532467f;
    const float A256 = 0.00567380f;   // alpha^256 — chunk carry multiplier

    const int lane = threadIdx.x & 63;
    const int wave = threadIdx.x >> 6;
    const int row  = blockIdx.x >> 2;            // 4 blocks per row
    const int cq   = (blockIdx.x & 3) * 4 + wave; // this wave's chunk, 0..15
    if (row >= nrows) return;

    const float* __restrict__ xr   = x   + (size_t)row * T_LEN;
    float* __restrict__       orow = out + (size_t)row * T_LEN;

    // ---- issue all loads up front: main chunk + up to 2 lookback chunks ----
    // chunks 0-2 use their FULL history (exact); cq>=3 truncate at 512 samples
    // (alpha^512 ~ 3.2e-5 — invisible vs threshold). Lookback chunks are <=14,
    // i.e. entirely in-bounds.
    const int nlb = (cq < 2) ? cq : 2;
    const int c0  = cq - nlb;                    // first lookback chunk index
    float4 vl0 = make_float4(0.f, 0.f, 0.f, 0.f);
    float4 vl1 = make_float4(0.f, 0.f, 0.f, 0.f);
    if (nlb > 0) vl0 = *reinterpret_cast<const float4*>(xr + c0 * CHUNK + lane * 4);
    if (nlb > 1) vl1 = *reinterpret_cast<const float4*>(xr + (c0 + 1) * CHUNK + lane * 4);
    const int t_main = cq * CHUNK + lane * 4;
    const bool valid = (t_main < T_LEN);         // only chunk 15 lanes >= 40 fail
    float4 vm = make_float4(0.f, 0.f, 0.f, 0.f);
    if (valid) vm = *reinterpret_cast<const float4*>(xr + t_main);

    // per-lane exclusive multiplier alpha^(4*lane)
    float powl = 1.0f;
    powl *= (lane & 1)  ? R1  : 1.0f;
    powl *= (lane & 2)  ? R2  : 1.0f;
    powl *= (lane & 4)  ? R4  : 1.0f;
    powl *= (lane & 8)  ? R8  : 1.0f;
    powl *= (lane & 16) ? R16 : 1.0f;
    powl *= (lane & 32) ? R32 : 1.0f;

    // ---- lookback: reconstruct state entering the main chunk ----
    // (branches are wave-uniform: nlb depends only on cq)
    float s_prev = 0.0f;
    if (nlb > 0) {
        const float b0  = compose4(vl0, (c0 == 0) && (lane == 0));
        const float bi0 = ks_scan(b0, lane);
        s_prev = __shfl(bi0, 63);                // c0==0 exact; else truncated
        if (nlb > 1) {
            const float b1  = compose4(vl1, false);
            const float bi1 = ks_scan(b1, lane);
            s_prev = fmaf(A256, s_prev, __shfl(bi1, 63));
        }
    }

    // ---- main chunk: scan, replay, epilogue, coalesced store ----
    const float bm  = compose4(vm, (cq == 0) && (lane == 0));
    const float bim = ks_scan(bm, lane);

    float be = __shfl_up(bim, 1);
    if (lane == 0) be = 0.0f;
    float s = fmaf(powl, s_prev, be);            // state entering lane's 4 elems

    if (valid) {
        float4 o;
        if (t_main == 0) s = vm.x;               // t=0: A=0, B=x0
        else             s = fmaf(ALPHA, s, OMA * vm.x);
        o.x = pcen_elem(vm.x, s);
        s = fmaf(ALPHA, s, OMA * vm.y);
        o.y = pcen_elem(vm.y, s);
        s = fmaf(ALPHA, s, OMA * vm.z);
        o.z = pcen_elem(vm.z, s);
        s = fmaf(ALPHA, s, OMA * vm.w);
        o.w = pcen_elem(vm.w, s);
        *reinterpret_cast<float4*>(orow + t_main) = o;
    }
}

extern "C" void kernel_launch(void* const* d_in, const int* in_sizes, int n_in,
                              void* d_out, int out_size, void* d_ws, size_t ws_size,
                              hipStream_t stream) {
    const float* x = (const float*)d_in[0];
    float* out = (float*)d_out;
    const int nrows = in_sizes[0] / T_LEN;   // 4096
    const int grid  = nrows * 4;             // 4 blocks/row, wave = 1 chunk
    pcen_kernel<<<grid, 256, 0, stream>>>(x, out, nrows);
}

// Round 7
// 111.424 us; speedup vs baseline: 1.0944x; 1.0944x over previous
//
#include <hip/hip_runtime.h>
#include <math.h>

#define T_LEN   4000
#define HALF    2000           // each wave owns half a row
#define CHUNK   256            // 64 lanes * 4 elements
#define NCHUNK  8              // ceil(2000/256); last chunk: lanes 0..51 valid
#define LB      2              // lookback chunks (512 elems; alpha^512 ~ 3e-5)

__device__ __forceinline__ float pcen_elem(float xv, float s) {
    const float ALPHA = 0.98f;
    const float DELTA = 2.0f;
    const float SQRT_DELTA = 1.4142135623730951f;
    const float EPS = 1e-6f;
    // native ops: v_log_f32 (base2), v_exp_f32 (base2), v_sqrt_f32 (~1 ulp)
    float p = __builtin_amdgcn_exp2f(-ALPHA * __builtin_amdgcn_logf(s + EPS));
    return __builtin_amdgcn_sqrtf(fmaf(xv, p, DELTA)) - SQRT_DELTA;
}

__global__ __launch_bounds__(256, 6) void pcen_kernel(const float* __restrict__ x,
                                                      float* __restrict__ out,
                                                      int nrows) {
    const float ALPHA = 0.98f;
    const float OMA   = 0.02f;
    // Rd = alpha^(4*d) — compile-time composed multipliers
    const float R1   = 0.92236816f;   // alpha^4
    const float R2   = 0.85076302f;   // alpha^8
    const float R4   = 0.72379773f;   // alpha^16
    const float R8   = 0.52388316f;   // alpha^32
    const float R16  = 0.27445340f;   // alpha^64
    const float R32  = 0.07532467f;   // alpha^128
    const float A256 = 0.00567380f;   // alpha^256 — per-chunk carry multiplier

    const int lane = threadIdx.x & 63;
    const int wave = threadIdx.x >> 6;
    const int wid  = blockIdx.x * 4 + wave;   // global wave id
    const int row  = wid >> 1;                // both halves of a row share a block
    const int half = wid & 1;
    if (row >= nrows) return;

    const float* __restrict__ xr   = x   + (size_t)row * T_LEN;
    float* __restrict__       orow = out + (size_t)row * T_LEN;
    const int base = half * HALF;

    // per-lane exclusive multiplier alpha^(4*lane)
    float powl = 1.0f;
    powl *= (lane & 1)  ? R1  : 1.0f;
    powl *= (lane & 2)  ? R2  : 1.0f;
    powl *= (lane & 4)  ? R4  : 1.0f;
    powl *= (lane & 8)  ? R8  : 1.0f;
    powl *= (lane & 16) ? R16 : 1.0f;
    powl *= (lane & 32) ? R32 : 1.0f;

    // ---- half 1: reconstruct entering state from a 512-sample lookback ----
    // s_2000 = sum_k alpha^k (1-alpha) x[1999-k], truncated at k=512
    // (alpha^512 ~ 3.3e-5 — far below the output threshold).
    float s_prev = 0.0f;
    if (half == 1) {
#pragma unroll
        for (int lb = 0; lb < LB; ++lb) {
            const int t0 = HALF - LB * CHUNK + lb * CHUNK + lane * 4;  // >= 1488
            const float4 vc = *reinterpret_cast<const float4*>(xr + t0);
            float b = OMA * vc.x;
            b = fmaf(ALPHA, b, OMA * vc.y);
            b = fmaf(ALPHA, b, OMA * vc.z);
            b = fmaf(ALPHA, b, OMA * vc.w);
            float bi = b;
            { float bu = __shfl_up(bi, 1);  bi = fmaf(lane >= 1  ? R1  : 0.f, bu, bi); }
            { float bu = __shfl_up(bi, 2);  bi = fmaf(lane >= 2  ? R2  : 0.f, bu, bi); }
            { float bu = __shfl_up(bi, 4);  bi = fmaf(lane >= 4  ? R4  : 0.f, bu, bi); }
            { float bu = __shfl_up(bi, 8);  bi = fmaf(lane >= 8  ? R8  : 0.f, bu, bi); }
            { float bu = __shfl_up(bi, 16); bi = fmaf(lane >= 16 ? R16 : 0.f, bu, bi); }
            { float bu = __shfl_up(bi, 32); bi = fmaf(lane >= 32 ? R32 : 0.f, bu, bi); }
            const float b63 = __shfl(bi, 63);
            s_prev = fmaf(A256, s_prev, b63);
        }
    }

    // ---- main: 8 chunks covering [base, base+2000) ----
#pragma unroll
    for (int c = 0; c < NCHUNK; ++c) {
        const int t0 = base + c * CHUNK + lane * 4;
        const bool valid = (t0 < base + HALF);   // tail chunk: lanes 0..51

        float4 vc = make_float4(0.f, 0.f, 0.f, 0.f);
        if (valid) vc = *reinterpret_cast<const float4*>(xr + t0);

        // local affine compose (b only; multiplier is constant alpha^4)
        float b = (t0 == 0) ? vc.x : OMA * vc.x;   // t=0: A=0, B=x0
        b = fmaf(ALPHA, b, OMA * vc.y);
        b = fmaf(ALPHA, b, OMA * vc.z);
        b = fmaf(ALPHA, b, OMA * vc.w);
        // invalid lanes: vc==0 -> b==0; they sit above all valid lanes and
        // the tail chunk's carry is never consumed.

        // constant-coefficient Kogge-Stone scan: one shuffle + one FMA per step
        float bi = b;
        { float bu = __shfl_up(bi, 1);  bi = fmaf(lane >= 1  ? R1  : 0.f, bu, bi); }
        { float bu = __shfl_up(bi, 2);  bi = fmaf(lane >= 2  ? R2  : 0.f, bu, bi); }
        { float bu = __shfl_up(bi, 4);  bi = fmaf(lane >= 4  ? R4  : 0.f, bu, bi); }
        { float bu = __shfl_up(bi, 8);  bi = fmaf(lane >= 8  ? R8  : 0.f, bu, bi); }
        { float bu = __shfl_up(bi, 16); bi = fmaf(lane >= 16 ? R16 : 0.f, bu, bi); }
        { float bu = __shfl_up(bi, 32); bi = fmaf(lane >= 32 ? R32 : 0.f, bu, bi); }

        // exclusive prefix + carry
        float be = __shfl_up(bi, 1);
        if (lane == 0) be = 0.0f;
        float s = fmaf(powl, s_prev, be);

        const float b63 = __shfl(bi, 63);
        s_prev = fmaf(A256, s_prev, b63);

        // replay 4 elems, epilogue, coalesced store
        if (valid) {
            float4 o;
            if (t0 == 0) s = vc.x;
            else         s = fmaf(ALPHA, s, OMA * vc.x);
            o.x = pcen_elem(vc.x, s);
            s = fmaf(ALPHA, s, OMA * vc.y);
            o.y = pcen_elem(vc.y, s);
            s = fmaf(ALPHA, s, OMA * vc.z);
            o.z = pcen_elem(vc.z, s);
            s = fmaf(ALPHA, s, OMA * vc.w);
            o.w = pcen_elem(vc.w, s);
            *reinterpret_cast<float4*>(orow + t0) = o;
        }
    }
}

extern "C" void kernel_launch(void* const* d_in, const int* in_sizes, int n_in,
                              void* d_out, int out_size, void* d_ws, size_t ws_size,
                              hipStream_t stream) {
    const float* x = (const float*)d_in[0];
    float* out = (float*)d_out;
    const int nrows = in_sizes[0] / T_LEN;     // 4096
    const int nwaves = nrows * 2;              // two half-row waves per row
    const int grid = (nwaves + 3) / 4;         // 4 waves (256 threads) per block
    pcen_kernel<<<grid, 256, 0, stream>>>(x, out, nrows);
}